// Round 12
// baseline (162.309 us; speedup 1.0000x reference)
//
#include <hip/hip_runtime.h>
#include <cstddef>

// Problem constants (n=2, c=128, h=w=96, hid=256, P=5, heads=8, d_k=16)
constexpr int Cc = 128;
constexpr int Hh = 96;
constexpr int Ww = 96;
constexpr int HW = Hh * Ww;      // 9216 pixels per image
constexpr int Nn = 2;

typedef __attribute__((ext_vector_type(2))) _Float16 f16x2;
typedef __attribute__((ext_vector_type(4))) _Float16 f16x4;
typedef __attribute__((ext_vector_type(8))) _Float16 f16x8;
typedef __attribute__((ext_vector_type(4))) float f32x4;

__device__ __forceinline__ float fdot2(f16x2 a, f16x2 b, float c) {
#if defined(__has_builtin) && __has_builtin(__builtin_amdgcn_fdot2)
    return __builtin_amdgcn_fdot2(a, b, c, false);
#else
    return (float)a[0] * (float)b[0] + (float)a[1] * (float)b[1] + c;
#endif
}

// ---------------------------------------------------------------------------
// Weight fp32 -> f16 in MFMA B-FRAGMENT ORDER (blocks 0..63):
//   dst[((mt*(K/32) + kc)*64 + lane)*8 + j] = W[mt*16+(lane&15)][kc*32+(lane>>4)*8+j]
// Offsets (halves): wq 0, wk 16384, wv 32768, wfc 49152, w1 65536, w2 98304.
// Blocks 64..79: W1' = W1 x Wfc (algebraic fc/mlp1 re-association), fp32
// accumulate from the original fp32 weights, stored f16 fragment-order.
// ---------------------------------------------------------------------------
__global__ void __launch_bounds__(256)
wcvt_k(const float* __restrict__ wq, const float* __restrict__ wk,
       const float* __restrict__ wv, const float* __restrict__ wfc,
       const float* __restrict__ w1, const float* __restrict__ w2,
       _Float16* __restrict__ dst, _Float16* __restrict__ w1p)
{
    if (blockIdx.x < 64) {
        const int h0 = (blockIdx.x * 256 + threadIdx.x) * 8;
        const float* src; int off, K;
        if (h0 < 16384)      { src = wq;  off = h0;          K = 128; }
        else if (h0 < 32768) { src = wk;  off = h0 - 16384;  K = 128; }
        else if (h0 < 49152) { src = wv;  off = h0 - 32768;  K = 128; }
        else if (h0 < 65536) { src = wfc; off = h0 - 49152;  K = 128; }
        else if (h0 < 98304) { src = w1;  off = h0 - 65536;  K = 128; }
        else                 { src = w2;  off = h0 - 98304;  K = 256; }
        const int fid  = off >> 3;
        const int lane = fid & 63;
        const int n16  = lane & 15, quad = lane >> 4;
        const int t2   = fid >> 6;
        const int kcN  = K / 32;
        const int kc   = t2 % kcN;
        const int mt   = t2 / kcN;
        const int row  = mt * 16 + n16;
        const int col  = kc * 32 + quad * 8;
        const float* s = src + (size_t)row * K + col;
        const float4 a = *(const float4*)s;
        const float4 b = *(const float4*)(s + 4);
        f16x8 h = {(_Float16)a.x, (_Float16)a.y, (_Float16)a.z, (_Float16)a.w,
                   (_Float16)b.x, (_Float16)b.y, (_Float16)b.z, (_Float16)b.w};
        *(f16x8*)&dst[h0] = h;
    } else {
        // W1'[r][c] = sum_oc w1[r][oc] * wfc[oc][c]; one f16x8 fragment/thread
        const int fid = (blockIdx.x - 64) * 256 + threadIdx.x;   // 0..4095
        const int lane = fid & 63;
        const int n16 = lane & 15, quad = lane >> 4;
        const int t2 = fid >> 6;           // 0..63
        const int kc = t2 & 3, mt = t2 >> 2;
        const int row = mt * 16 + n16;     // 0..255
        const int ic0 = kc * 32 + quad * 8;
        const float* w1row = w1 + (size_t)row * 128;
        float acc[8] = {0.f, 0.f, 0.f, 0.f, 0.f, 0.f, 0.f, 0.f};
#pragma unroll 4
        for (int oc = 0; oc < 128; ++oc) {
            const float wv = w1row[oc];
            const float4 f0 = *(const float4*)&wfc[(size_t)oc * 128 + ic0];
            const float4 f1 = *(const float4*)&wfc[(size_t)oc * 128 + ic0 + 4];
            acc[0] = fmaf(wv, f0.x, acc[0]); acc[1] = fmaf(wv, f0.y, acc[1]);
            acc[2] = fmaf(wv, f0.z, acc[2]); acc[3] = fmaf(wv, f0.w, acc[3]);
            acc[4] = fmaf(wv, f1.x, acc[4]); acc[5] = fmaf(wv, f1.y, acc[5]);
            acc[6] = fmaf(wv, f1.z, acc[6]); acc[7] = fmaf(wv, f1.w, acc[7]);
        }
        f16x8 h;
#pragma unroll
        for (int j = 0; j < 8; ++j) h[j] = (_Float16)acc[j];
        *(f16x8*)&w1p[(size_t)fid * 8] = h;
    }
}

// ---------------------------------------------------------------------------
// Fused q/k/v projections. X fp32 NCHW staged once to f16 k-major LDS;
// both 64-oc halves from the same tile (A-fragments hoisted and reused).
// B-frags from fragment-order weights. All outputs f16 NHWC.
// grid (HW/64, 3, Nn), block 128.
// ---------------------------------------------------------------------------
__global__ void __launch_bounds__(128)
qkv_k(const float* __restrict__ Xq, const float* __restrict__ Xk,
      const float* __restrict__ Xv, const _Float16* __restrict__ w16,
      _Float16* __restrict__ q16, _Float16* __restrict__ k16,
      _Float16* __restrict__ v16)
{
    const int t  = blockIdx.y;
    const int p0 = blockIdx.x * 64;
    const int z  = blockIdx.z;
    const float* X = (t == 0) ? Xq : (t == 1) ? Xk : Xv;
    _Float16* Y    = (t == 0) ? q16 : (t == 1) ? k16 : v16;
    const _Float16* W = w16 + (size_t)t * 16384;

    __shared__ _Float16 xl[128][72];   // [k][px]
    const int tid = threadIdx.x;
    {
        const int px4 = (tid & 15) * 4, kg = tid >> 4;
        const float* Xz = X + (size_t)z * Cc * HW + p0 + px4;
#pragma unroll
        for (int kk = 0; kk < 16; ++kk) {
            const int k = kk * 8 + kg;
            float4 a = *(const float4*)&Xz[(size_t)k * HW];
            f16x4 h = {(_Float16)a.x, (_Float16)a.y, (_Float16)a.z, (_Float16)a.w};
            *(f16x4*)&xl[k][px4] = h;
        }
    }
    __syncthreads();

    const int w = tid >> 6, lane = tid & 63;
    const int n16 = lane & 15, quad = lane >> 4;
    const int pw = w * 32;

    // hoisted A-fragments: independent of output-channel half
    f16x8 A[2][4];
#pragma unroll
    for (int mi = 0; mi < 2; ++mi) {
        const int px = pw + mi * 16 + n16;
#pragma unroll
        for (int kcid = 0; kcid < 4; ++kcid) {
            f16x8 av;
#pragma unroll
            for (int j = 0; j < 8; ++j) av[j] = xl[kcid * 32 + quad * 8 + j][px];
            A[mi][kcid] = av;
        }
    }

#pragma unroll
    for (int half = 0; half < 2; ++half) {
        const int oc0 = half * 64;
        f32x4 acc[2][4];
#pragma unroll
        for (int mi = 0; mi < 2; ++mi)
#pragma unroll
            for (int ni = 0; ni < 4; ++ni) acc[mi][ni] = (f32x4)0.f;

#pragma unroll
        for (int kcid = 0; kcid < 4; ++kcid) {
            f16x8 B[4];
#pragma unroll
            for (int ni = 0; ni < 4; ++ni)
                B[ni] = *(const f16x8*)&W[(((half * 4 + ni) * 4 + kcid) * 64 + lane) * 8];
#pragma unroll
            for (int mi = 0; mi < 2; ++mi)
#pragma unroll
                for (int ni = 0; ni < 4; ++ni)
                    acc[mi][ni] = __builtin_amdgcn_mfma_f32_16x16x32_f16(
                        A[mi][kcid], B[ni], acc[mi][ni], 0, 0, 0);
        }

#pragma unroll
        for (int mi = 0; mi < 2; ++mi)
#pragma unroll
            for (int r = 0; r < 4; ++r) {
                const int pix = p0 + pw + mi * 16 + quad * 4 + r;
                const size_t base = ((size_t)z * HW + pix) * Cc + oc0;
#pragma unroll
                for (int ni = 0; ni < 4; ++ni)
                    Y[base + ni * 16 + n16] = (_Float16)acc[mi][ni][r];
            }
    }
}

// ---------------------------------------------------------------------------
// Fused fc + mlp1 (both depend only on at16, thanks to W1' = W1 x Wfc):
// tiles 0-1: y1 = wfc @ at (f16, 128-wide). tiles 2-5: h = lrelu(W1'@at+b1)
// (f16, 256-wide). One wave = 32 px x 64 oc. grid (HW/64, 6, Nn), block 128.
// ---------------------------------------------------------------------------
__global__ void __launch_bounds__(128)
fcm_k(const _Float16* __restrict__ at, const _Float16* __restrict__ wfcF,
      const _Float16* __restrict__ w1pF, const float* __restrict__ b1,
      _Float16* __restrict__ y1, _Float16* __restrict__ hb)
{
    const int ty = blockIdx.y;
    const bool isFc = ty < 2;
    const int tile = isFc ? ty : ty - 2;
    const int oc0 = tile * 64;
    const _Float16* Wf = isFc ? wfcF : w1pF;
    const int Mtot = isFc ? 128 : 256;
    _Float16* Y = isFc ? y1 : hb;

    const int z = blockIdx.z, p0 = blockIdx.x * 64;
    const int tid = threadIdx.x, w = tid >> 6, lane = tid & 63;
    const int n16 = lane & 15, quad = lane >> 4;
    const _Float16* Xz = at + ((size_t)z * HW + p0 + w * 32) * 128;

    f32x4 acc[2][4];
#pragma unroll
    for (int mi = 0; mi < 2; ++mi)
#pragma unroll
        for (int ni = 0; ni < 4; ++ni) acc[mi][ni] = (f32x4)0.f;

#pragma unroll
    for (int kc = 0; kc < 4; ++kc) {
        f16x8 A[2], B[4];
#pragma unroll
        for (int mi = 0; mi < 2; ++mi)
            A[mi] = *(const f16x8*)&Xz[(size_t)(mi * 16 + n16) * 128 + kc * 32 + quad * 8];
#pragma unroll
        for (int ni = 0; ni < 4; ++ni)
            B[ni] = *(const f16x8*)&Wf[(((tile * 4 + ni) * 4 + kc) * 64 + lane) * 8];
#pragma unroll
        for (int mi = 0; mi < 2; ++mi)
#pragma unroll
            for (int ni = 0; ni < 4; ++ni)
                acc[mi][ni] = __builtin_amdgcn_mfma_f32_16x16x32_f16(
                    A[mi], B[ni], acc[mi][ni], 0, 0, 0);
    }

    float bv[4];
#pragma unroll
    for (int ni = 0; ni < 4; ++ni) bv[ni] = isFc ? 0.f : b1[oc0 + ni * 16 + n16];

#pragma unroll
    for (int mi = 0; mi < 2; ++mi)
#pragma unroll
        for (int r = 0; r < 4; ++r) {
            const int pix = p0 + w * 32 + mi * 16 + quad * 4 + r;
            const size_t ob = ((size_t)z * HW + pix) * (size_t)Mtot + oc0;
#pragma unroll
            for (int ni = 0; ni < 4; ++ni) {
                float tv = acc[mi][ni][r] + bv[ni];
                if (!isFc) tv = tv >= 0.f ? tv : 0.2f * tv;
                Y[ob + ni * 16 + n16] = (_Float16)tv;
            }
        }
}

// ---------------------------------------------------------------------------
// MFMA GEMM (mlp2): one wave = 32 pixels x 64 oc. A-frags from NHWC f16
// global; B-frags from fragment-order weights. Block 128 thr = 2 waves.
// grid (HW/64, 2, Nn). Per-block partial (sum,sumsq) -> pb[], no atomics.
// ---------------------------------------------------------------------------
template<int KT, bool OUTF16, bool BIAS, bool LRELU, bool RESID, bool REDUCE>
__global__ void __launch_bounds__(128)
mg_k(const _Float16* __restrict__ X, const _Float16* __restrict__ Wf,
     const float* __restrict__ bias, const _Float16* __restrict__ resid,
     void* __restrict__ Yv, float* __restrict__ pb, const int Mtot)
{
    constexpr int kcN = KT / 32;
    const int z = blockIdx.z, oc0 = blockIdx.y * 64, p0 = blockIdx.x * 64;
    const int tid = threadIdx.x, w = tid >> 6, lane = tid & 63;
    const int n16 = lane & 15, quad = lane >> 4;
    const _Float16* Xz = X + ((size_t)z * HW + p0 + w * 32) * KT;

    f32x4 acc[2][4];
#pragma unroll
    for (int mi = 0; mi < 2; ++mi)
#pragma unroll
        for (int ni = 0; ni < 4; ++ni) acc[mi][ni] = (f32x4)0.f;

#pragma unroll
    for (int kc = 0; kc < kcN; ++kc) {
        f16x8 A[2], B[4];
#pragma unroll
        for (int mi = 0; mi < 2; ++mi)
            A[mi] = *(const f16x8*)&Xz[(size_t)(mi * 16 + n16) * KT + kc * 32 + quad * 8];
#pragma unroll
        for (int ni = 0; ni < 4; ++ni)
            B[ni] = *(const f16x8*)&Wf[(((blockIdx.y * 4 + ni) * kcN + kc) * 64 + lane) * 8];
#pragma unroll
        for (int mi = 0; mi < 2; ++mi)
#pragma unroll
            for (int ni = 0; ni < 4; ++ni)
                acc[mi][ni] = __builtin_amdgcn_mfma_f32_16x16x32_f16(
                    A[mi], B[ni], acc[mi][ni], 0, 0, 0);
    }

    float bv[4];
#pragma unroll
    for (int ni = 0; ni < 4; ++ni) bv[ni] = BIAS ? bias[oc0 + ni * 16 + n16] : 0.f;

    float lsum = 0.f, lsq = 0.f;
#pragma unroll
    for (int mi = 0; mi < 2; ++mi)
#pragma unroll
        for (int r = 0; r < 4; ++r) {
            const int pix = p0 + w * 32 + mi * 16 + quad * 4 + r;
            const size_t ob = ((size_t)z * HW + pix) * (size_t)Mtot + oc0;
            const size_t rb = ((size_t)z * HW + pix) * 128 + oc0;
#pragma unroll
            for (int ni = 0; ni < 4; ++ni) {
                float tv = acc[mi][ni][r] + bv[ni];
                if (LRELU) tv = tv >= 0.f ? tv : 0.2f * tv;
                if (RESID) tv += (float)resid[rb + ni * 16 + n16];
                if (REDUCE) { lsum += tv; lsq += tv * tv; }
                if (OUTF16) ((_Float16*)Yv)[ob + ni * 16 + n16] = (_Float16)tv;
                else        ((float*)Yv)[ob + ni * 16 + n16] = tv;
            }
        }

    if (REDUCE) {
        __shared__ float red[4];
#pragma unroll
        for (int m = 1; m < 64; m <<= 1) {
            lsum += __shfl_xor(lsum, m, 64);
            lsq  += __shfl_xor(lsq,  m, 64);
        }
        if (lane == 0) { red[w * 2] = lsum; red[w * 2 + 1] = lsq; }
        __syncthreads();
        if (tid == 0) {
            const int bid = (blockIdx.z * gridDim.y + blockIdx.y) * gridDim.x + blockIdx.x;
            pb[bid * 2 + 0] = red[0] + red[2];
            pb[bid * 2 + 1] = red[1] + red[3];
        }
    }
}

// ---------------------------------------------------------------------------
// Deformable window attention, 4 pixels per wave (16 lanes/pixel, 8 ch/lane).
// q,k,v f16 NHWC. QK via v_dot2_f32_f16; PV via mixed fma (fp32 acc).
// Separable (Wy x Wx) spread of attn into the 6x6 tap field.
// ---------------------------------------------------------------------------
__global__ void __launch_bounds__(256)
attn_k(const _Float16* __restrict__ q, const _Float16* __restrict__ k,
       const _Float16* __restrict__ v, const float* __restrict__ df,
       _Float16* __restrict__ out)
{
    const int blk = blockIdx.x;
    const int sw = (blk & 7) * (1152 / 8) + (blk >> 3);   // XCD band swizzle
    const int wv = sw * 4 + (threadIdx.x >> 6);
    const int lane = threadIdx.x & 63;
    const int gp = wv * 4 + (lane >> 4);                  // global pixel
    const int b = gp / HW;
    const int pix = gp - b * HW;
    const int y = pix / Ww, x = pix - y * Ww;
    const int co = (lane & 15) * 8;                       // channel offset

    const float dx = df[((size_t)b * 2 + 0) * HW + pix];
    const float dy = df[((size_t)b * 2 + 1) * HW + pix];
    const float flx = floorf(dx), fly = floorf(dy);
    const int bx = x - 2 + (int)flx;
    const int by = y - 2 + (int)fly;
    const float wx1 = dx - flx, wx0 = 1.f - wx1;
    const float wy1 = dy - fly, wy0 = 1.f - wy1;
    const float u00 = wy0 * wx0, u01 = wy0 * wx1, u10 = wy1 * wx0, u11 = wy1 * wx1;
    const float s00 = u00 * 0.25f, s01 = u01 * 0.25f,
                s10 = u10 * 0.25f, s11 = u11 * 0.25f;

    const f16x8 qv8 = *(const f16x8*)&q[((size_t)b * HW + pix) * Cc + co];
    const f16x2 q0 = {qv8[0], qv8[1]}, q1 = {qv8[2], qv8[3]},
                q2 = {qv8[4], qv8[5]}, q3 = {qv8[6], qv8[7]};

    const _Float16* kp = k + ((size_t)b * HW) * Cc + co;
    const _Float16* vp = v + ((size_t)b * HW) * Cc + co;

    const bool inb = (bx >= 0) & (by >= 0) & (bx <= Ww - 6) & (by <= Hh - 6);
    const int allin = __all(inb);

    float qk[36];
    if (allin) {
        const _Float16* kr = kp + (size_t)(by * Ww + bx) * Cc;
#pragma unroll
        for (int r = 0; r < 6; ++r) {
#pragma unroll
            for (int c = 0; c < 6; ++c) {
                const f16x8 kv = *(const f16x8*)&kr[c * Cc];
                f16x2 k0 = {kv[0], kv[1]}, k1 = {kv[2], kv[3]};
                f16x2 k2 = {kv[4], kv[5]}, k3 = {kv[6], kv[7]};
                float d = fdot2(q0, k0, 0.f);
                d = fdot2(q1, k1, d);
                d = fdot2(q2, k2, d);
                d = fdot2(q3, k3, d);
                qk[r * 6 + c] = d;
            }
            kr += Ww * Cc;
        }
    } else {
#pragma unroll
        for (int r = 0; r < 6; ++r) {
            const int yr = by + r;
            const bool rv = (yr >= 0) & (yr < Hh);
            const int yc = min(max(yr, 0), Hh - 1);
            const _Float16* kr = kp + (size_t)(yc * Ww) * Cc;
#pragma unroll
            for (int c = 0; c < 6; ++c) {
                const int xc = bx + c;
                const bool cv = rv & (xc >= 0) & (xc < Ww);
                const int xcc = min(max(xc, 0), Ww - 1);
                const f16x8 kv = *(const f16x8*)&kr[xcc * Cc];
                f16x2 k0 = {kv[0], kv[1]}, k1 = {kv[2], kv[3]};
                f16x2 k2 = {kv[4], kv[5]}, k3 = {kv[6], kv[7]};
                float d = fdot2(q0, k0, 0.f);
                d = fdot2(q1, k1, d);
                d = fdot2(q2, k2, d);
                d = fdot2(q3, k3, d);
                qk[r * 6 + c] = cv ? d : 0.f;
            }
        }
    }

    float a[25];
#pragma unroll
    for (int py = 0; py < 5; ++py)
#pragma unroll
        for (int px = 0; px < 5; ++px) {
            float tv = s00 * qk[py * 6 + px];
            tv = fmaf(s01, qk[py * 6 + px + 1], tv);
            tv = fmaf(s10, qk[(py + 1) * 6 + px], tv);
            tv = fmaf(s11, qk[(py + 1) * 6 + px + 1], tv);
            a[py * 5 + px] = tv;
        }
#pragma unroll
    for (int i = 0; i < 25; ++i) a[i] += __shfl_xor(a[i], 1, 64);

    float mx = a[0];
#pragma unroll
    for (int i = 1; i < 25; ++i) mx = fmaxf(mx, a[i]);
    float ssum = 0.f;
#pragma unroll
    for (int i = 0; i < 25; ++i) { a[i] = __expf(a[i] - mx); ssum += a[i]; }
    const float inv = 1.f / ssum;

    // separable spread: rows (Wy) then cols (Wx)
    float tmp[6][5];
#pragma unroll
    for (int r = 0; r < 6; ++r)
#pragma unroll
        for (int px = 0; px < 5; ++px) {
            float tv = 0.f;
            if (r < 5)  tv = a[r * 5 + px] * wy0;
            if (r >= 1) tv = fmaf(a[(r - 1) * 5 + px], wy1, tv);
            tmp[r][px] = tv;
        }
    float wsum[36];
#pragma unroll
    for (int r = 0; r < 6; ++r)
#pragma unroll
        for (int c = 0; c < 6; ++c) {
            float tv = 0.f;
            if (c < 5)  tv = tmp[r][c] * wx0;
            if (c >= 1) tv = fmaf(tmp[r][c - 1], wx1, tv);
            wsum[r * 6 + c] = tv;
        }

    float o[8] = {0.f, 0.f, 0.f, 0.f, 0.f, 0.f, 0.f, 0.f};
    if (allin) {
        const _Float16* vr = vp + (size_t)(by * Ww + bx) * Cc;
#pragma unroll
        for (int r = 0; r < 6; ++r) {
#pragma unroll
            for (int c = 0; c < 6; ++c) {
                const f16x8 vv = *(const f16x8*)&vr[c * Cc];
                const float wgt = wsum[r * 6 + c];
#pragma unroll
                for (int j = 0; j < 8; ++j)
                    o[j] = fmaf(wgt, (float)vv[j], o[j]);
            }
            vr += Ww * Cc;
        }
    } else {
#pragma unroll
        for (int r = 0; r < 6; ++r) {
            const int yr = by + r;
            const bool rv = (yr >= 0) & (yr < Hh);
            const int yc = min(max(yr, 0), Hh - 1);
            const _Float16* vr = vp + (size_t)(yc * Ww) * Cc;
#pragma unroll
            for (int c = 0; c < 6; ++c) {
                const int xc = bx + c;
                const bool cv = rv & (xc >= 0) & (xc < Ww);
                const int xcc = min(max(xc, 0), Ww - 1);
                const f16x8 vv = *(const f16x8*)&vr[xcc * Cc];
                const float wgt = cv ? wsum[r * 6 + c] : 0.f;
#pragma unroll
                for (int j = 0; j < 8; ++j)
                    o[j] = fmaf(wgt, (float)vv[j], o[j]);
            }
        }
    }

    f16x8 ov;
#pragma unroll
    for (int j = 0; j < 8; ++j) ov[j] = (_Float16)(o[j] * inv);
    *(f16x8*)&out[((size_t)b * HW + pix) * Cc + co] = ov;
}

// ---------------------------------------------------------------------------
// GroupNorm finalize + NHWC fp32 -> NCHW fp32 transpose, with inline
// reduction of the mlp2 per-block partials. grid (HW/64, Cc/32, Nn), block 256.
// ---------------------------------------------------------------------------
__global__ void __launch_bounds__(256)
gn_k(const float* __restrict__ y2, const float* __restrict__ pb,
     const float* __restrict__ gamma, const float* __restrict__ beta,
     float* __restrict__ out, const int nPerZ)
{
    __shared__ float t[32][68];
    __shared__ float redm[8];
    __shared__ float stats[2];
    const int z = blockIdx.z, c0 = blockIdx.y * 32, p0 = blockIdx.x * 64;
    const int tid = threadIdx.x;

    // inline partial reduction (L2-hot, 2.3 KB per z)
    {
        float s = 0.f, qq = 0.f;
        for (int p = tid; p < nPerZ; p += 256) {
            s  += pb[(z * nPerZ + p) * 2 + 0];
            qq += pb[(z * nPerZ + p) * 2 + 1];
        }
#pragma unroll
        for (int m = 1; m < 64; m <<= 1) {
            s  += __shfl_xor(s,  m, 64);
            qq += __shfl_xor(qq, m, 64);
        }
        if ((tid & 63) == 0) {
            redm[(tid >> 6) * 2]     = s;
            redm[(tid >> 6) * 2 + 1] = qq;
        }
    }
    // stage the transpose tile
    {
        const int px = tid >> 2, cq = tid & 3;
        const float* src = &y2[((size_t)z * HW + p0 + px) * Cc + c0 + cq * 8];
        const float4 a = *(const float4*)src;
        const float4 bq = *(const float4*)(src + 4);
        t[cq * 8 + 0][px] = a.x;  t[cq * 8 + 1][px] = a.y;
        t[cq * 8 + 2][px] = a.z;  t[cq * 8 + 3][px] = a.w;
        t[cq * 8 + 4][px] = bq.x; t[cq * 8 + 5][px] = bq.y;
        t[cq * 8 + 6][px] = bq.z; t[cq * 8 + 7][px] = bq.w;
    }
    __syncthreads();
    if (tid == 0) {
        const float invN = 1.f / (float)(Cc * HW);
        const float S = redm[0] + redm[2] + redm[4] + redm[6];
        const float Q = redm[1] + redm[3] + redm[5] + redm[7];
        const float mean = S * invN;
        const float var  = fmaf(-mean, mean, Q * invN);
        stats[0] = mean;
        stats[1] = rsqrtf(var + 1e-5f);
    }
    __syncthreads();
    {
        const float mean = stats[0], rs = stats[1];
        const int c = tid >> 3, pq = tid & 7;
        const float g = gamma[c0 + c] * rs, be = beta[c0 + c];
        float4 o1, o2;
        o1.x = fmaf(t[c][pq * 8 + 0] - mean, g, be);
        o1.y = fmaf(t[c][pq * 8 + 1] - mean, g, be);
        o1.z = fmaf(t[c][pq * 8 + 2] - mean, g, be);
        o1.w = fmaf(t[c][pq * 8 + 3] - mean, g, be);
        o2.x = fmaf(t[c][pq * 8 + 4] - mean, g, be);
        o2.y = fmaf(t[c][pq * 8 + 5] - mean, g, be);
        o2.z = fmaf(t[c][pq * 8 + 6] - mean, g, be);
        o2.w = fmaf(t[c][pq * 8 + 7] - mean, g, be);
        float* dst = &out[((size_t)z * Cc + c0 + c) * HW + p0 + pq * 8];
        *(float4*)dst = o1;
        *(float4*)(dst + 4) = o2;
    }
}

// ---------------------------------------------------------------------------
extern "C" void kernel_launch(void* const* d_in, const int* in_sizes, int n_in,
                              void* d_out, int out_size, void* d_ws, size_t ws_size,
                              hipStream_t stream)
{
    const float* query  = (const float*)d_in[0];
    const float* key    = (const float*)d_in[1];
    const float* value  = (const float*)d_in[2];
    const float* deform = (const float*)d_in[3];
    const float* w_q    = (const float*)d_in[4];
    const float* w_k    = (const float*)d_in[5];
    const float* w_v    = (const float*)d_in[6];
    const float* w_fc   = (const float*)d_in[7];
    const float* mlp_w1 = (const float*)d_in[8];
    const float* mlp_b1 = (const float*)d_in[9];
    const float* mlp_w2 = (const float*)d_in[10];
    const float* mlp_b2 = (const float*)d_in[11];
    const float* gn_g   = (const float*)d_in[12];
    const float* gn_b   = (const float*)d_in[13];
    float* out = (float*)d_out;

    // workspace layout
    char* wsb = (char*)d_ws;
    _Float16* w16 = (_Float16*)wsb;                  // 131072 halves, frag order
    _Float16* w1p = (_Float16*)(wsb + 262144);       // 32768 halves, W1' frag order
    float* pb   = (float*)(wsb + 327680);            // per-block partials
    _Float16* T = (_Float16*)(wsb + 524288);
    const size_t S16 = (size_t)Nn * HW * Cc;         // halves per f16 tensor
    _Float16* q16  = T;                              // R0
    _Float16* k16  = T + S16;                        // R1
    _Float16* v16  = T + 2 * S16;                    // R2
    _Float16* at16 = T + 3 * S16;                    // R3
    _Float16* y1   = T + 4 * S16;                    // R4
    _Float16* hb   = T;                              // R0+R1 (q,k dead after attn)
    float*    y2   = (float*)(T + 2 * S16);          // R2+R3 (v,at dead by mlp2)

    // weights -> f16 fragment order; blocks 64..79 compute W1' = W1 x Wfc
    wcvt_k<<<dim3(80), dim3(256), 0, stream>>>(
        w_q, w_k, w_v, w_fc, mlp_w1, mlp_w2, w16, w1p);

    // fused q/k/v projections -> f16 NHWC
    qkv_k<<<dim3(HW / 64, 3, Nn), dim3(128), 0, stream>>>(
        query, key, value, w16, q16, k16, v16);

    // deformable window attention -> f16 NHWC
    attn_k<<<dim3(Nn * HW / 16), dim3(256), 0, stream>>>(
        q16, k16, v16, deform, at16);

    // fused fc + mlp1 (both from at16): y1 and h in one dispatch
    fcm_k<<<dim3(HW / 64, 6, Nn), dim3(128), 0, stream>>>(
        at16, w16 + 49152, w1p, mlp_b1, y1, hb);

    // y2 = y1 + w2 @ h + b2 (fp32 NHWC), per-block partial sums
    mg_k<256, false, true, false, true, true>
        <<<dim3(HW / 64, 2, Nn), dim3(128), 0, stream>>>(
        hb, w16 + 98304, mlp_b2, y1, y2, pb, 128);

    // GroupNorm finalize (inline partial reduce) + NHWC->NCHW
    gn_k<<<dim3(HW / 64, Cc / 32, Nn), dim3(256), 0, stream>>>(
        y2, pb, gn_g, gn_b, out, 288);
}

// Round 13
// 154.724 us; speedup vs baseline: 1.0490x; 1.0490x over previous
//
#include <hip/hip_runtime.h>
#include <cstddef>

// Problem constants (n=2, c=128, h=w=96, hid=256, P=5, heads=8, d_k=16)
constexpr int Cc = 128;
constexpr int Hh = 96;
constexpr int Ww = 96;
constexpr int HW = Hh * Ww;      // 9216 pixels per image
constexpr int Nn = 2;

typedef __attribute__((ext_vector_type(2))) _Float16 f16x2;
typedef __attribute__((ext_vector_type(4))) _Float16 f16x4;
typedef __attribute__((ext_vector_type(8))) _Float16 f16x8;
typedef __attribute__((ext_vector_type(4))) float f32x4;

__device__ __forceinline__ float fdot2(f16x2 a, f16x2 b, float c) {
#if defined(__has_builtin) && __has_builtin(__builtin_amdgcn_fdot2)
    return __builtin_amdgcn_fdot2(a, b, c, false);
#else
    return (float)a[0] * (float)b[0] + (float)a[1] * (float)b[1] + c;
#endif
}

// ---------------------------------------------------------------------------
// Weight fp32 -> f16 in MFMA B-FRAGMENT ORDER:
//   dst[((mt*(K/32) + kc)*64 + lane)*8 + j] = W[mt*16+(lane&15)][kc*32+(lane>>4)*8+j]
// Offsets (halves): wq 0, wk 16384, wv 32768, wfc 49152, w1 65536, w2 98304.
// ---------------------------------------------------------------------------
__global__ void __launch_bounds__(256)
wcvt_k(const float* __restrict__ wq, const float* __restrict__ wk,
       const float* __restrict__ wv, const float* __restrict__ wfc,
       const float* __restrict__ w1, const float* __restrict__ w2,
       _Float16* __restrict__ dst)
{
    const int h0 = (blockIdx.x * 256 + threadIdx.x) * 8;
    const float* src; int off, K;
    if (h0 < 16384)      { src = wq;  off = h0;          K = 128; }
    else if (h0 < 32768) { src = wk;  off = h0 - 16384;  K = 128; }
    else if (h0 < 49152) { src = wv;  off = h0 - 32768;  K = 128; }
    else if (h0 < 65536) { src = wfc; off = h0 - 49152;  K = 128; }
    else if (h0 < 98304) { src = w1;  off = h0 - 65536;  K = 128; }
    else                 { src = w2;  off = h0 - 98304;  K = 256; }
    const int fid  = off >> 3;
    const int lane = fid & 63;
    const int n16  = lane & 15, quad = lane >> 4;
    const int t2   = fid >> 6;
    const int kcN  = K / 32;
    const int kc   = t2 % kcN;
    const int mt   = t2 / kcN;
    const int row  = mt * 16 + n16;
    const int col  = kc * 32 + quad * 8;
    const float* s = src + (size_t)row * K + col;
    const float4 a = *(const float4*)s;
    const float4 b = *(const float4*)(s + 4);
    f16x8 h = {(_Float16)a.x, (_Float16)a.y, (_Float16)a.z, (_Float16)a.w,
               (_Float16)b.x, (_Float16)b.y, (_Float16)b.z, (_Float16)b.w};
    *(f16x8*)&dst[h0] = h;
}

// ---------------------------------------------------------------------------
// Fused q/k/v projections. X fp32 NCHW staged once to f16 k-major LDS;
// both 64-oc halves from the same tile (A-fragments hoisted and reused).
// B-frags from fragment-order weights. All outputs f16 NHWC.
// grid (HW/64, 3, Nn), block 128.
// ---------------------------------------------------------------------------
__global__ void __launch_bounds__(128)
qkv_k(const float* __restrict__ Xq, const float* __restrict__ Xk,
      const float* __restrict__ Xv, const _Float16* __restrict__ w16,
      _Float16* __restrict__ q16, _Float16* __restrict__ k16,
      _Float16* __restrict__ v16)
{
    const int t  = blockIdx.y;
    const int p0 = blockIdx.x * 64;
    const int z  = blockIdx.z;
    const float* X = (t == 0) ? Xq : (t == 1) ? Xk : Xv;
    _Float16* Y    = (t == 0) ? q16 : (t == 1) ? k16 : v16;
    const _Float16* W = w16 + (size_t)t * 16384;

    __shared__ _Float16 xl[128][72];   // [k][px]
    const int tid = threadIdx.x;
    {
        const int px4 = (tid & 15) * 4, kg = tid >> 4;
        const float* Xz = X + (size_t)z * Cc * HW + p0 + px4;
#pragma unroll
        for (int kk = 0; kk < 16; ++kk) {
            const int k = kk * 8 + kg;
            float4 a = *(const float4*)&Xz[(size_t)k * HW];
            f16x4 h = {(_Float16)a.x, (_Float16)a.y, (_Float16)a.z, (_Float16)a.w};
            *(f16x4*)&xl[k][px4] = h;
        }
    }
    __syncthreads();

    const int w = tid >> 6, lane = tid & 63;
    const int n16 = lane & 15, quad = lane >> 4;
    const int pw = w * 32;

    // hoisted A-fragments: independent of output-channel half
    f16x8 A[2][4];
#pragma unroll
    for (int mi = 0; mi < 2; ++mi) {
        const int px = pw + mi * 16 + n16;
#pragma unroll
        for (int kcid = 0; kcid < 4; ++kcid) {
            f16x8 av;
#pragma unroll
            for (int j = 0; j < 8; ++j) av[j] = xl[kcid * 32 + quad * 8 + j][px];
            A[mi][kcid] = av;
        }
    }

#pragma unroll
    for (int half = 0; half < 2; ++half) {
        const int oc0 = half * 64;
        f32x4 acc[2][4];
#pragma unroll
        for (int mi = 0; mi < 2; ++mi)
#pragma unroll
            for (int ni = 0; ni < 4; ++ni) acc[mi][ni] = (f32x4)0.f;

#pragma unroll
        for (int kcid = 0; kcid < 4; ++kcid) {
            f16x8 B[4];
#pragma unroll
            for (int ni = 0; ni < 4; ++ni)
                B[ni] = *(const f16x8*)&W[(((half * 4 + ni) * 4 + kcid) * 64 + lane) * 8];
#pragma unroll
            for (int mi = 0; mi < 2; ++mi)
#pragma unroll
                for (int ni = 0; ni < 4; ++ni)
                    acc[mi][ni] = __builtin_amdgcn_mfma_f32_16x16x32_f16(
                        A[mi][kcid], B[ni], acc[mi][ni], 0, 0, 0);
        }

#pragma unroll
        for (int mi = 0; mi < 2; ++mi)
#pragma unroll
            for (int r = 0; r < 4; ++r) {
                const int pix = p0 + pw + mi * 16 + quad * 4 + r;
                const size_t base = ((size_t)z * HW + pix) * Cc + oc0;
#pragma unroll
                for (int ni = 0; ni < 4; ++ni)
                    Y[base + ni * 16 + n16] = (_Float16)acc[mi][ni][r];
            }
    }
}

// ---------------------------------------------------------------------------
// MFMA GEMM: one wave = 32 pixels x 64 oc (A[2], B[4], 8 MFMA per K-step).
// A-frags straight from NHWC f16 global; B-frags from fragment-order weights.
// Block 128 thr = 2 waves. grid (HW/64, Mtot/64, Nn).
// REDUCE: per-block partial (sum,sumsq) -> pb[], no atomics.
// ---------------------------------------------------------------------------
template<int KT, bool OUTF16, bool BIAS, bool LRELU, bool RESID, bool REDUCE>
__global__ void __launch_bounds__(128)
mg_k(const _Float16* __restrict__ X, const _Float16* __restrict__ Wf,
     const float* __restrict__ bias, const _Float16* __restrict__ resid,
     void* __restrict__ Yv, float* __restrict__ pb, const int Mtot)
{
    constexpr int kcN = KT / 32;
    const int z = blockIdx.z, oc0 = blockIdx.y * 64, p0 = blockIdx.x * 64;
    const int tid = threadIdx.x, w = tid >> 6, lane = tid & 63;
    const int n16 = lane & 15, quad = lane >> 4;
    const _Float16* Xz = X + ((size_t)z * HW + p0 + w * 32) * KT;

    f32x4 acc[2][4];
#pragma unroll
    for (int mi = 0; mi < 2; ++mi)
#pragma unroll
        for (int ni = 0; ni < 4; ++ni) acc[mi][ni] = (f32x4)0.f;

#pragma unroll
    for (int kc = 0; kc < kcN; ++kc) {
        f16x8 A[2], B[4];
#pragma unroll
        for (int mi = 0; mi < 2; ++mi)
            A[mi] = *(const f16x8*)&Xz[(size_t)(mi * 16 + n16) * KT + kc * 32 + quad * 8];
#pragma unroll
        for (int ni = 0; ni < 4; ++ni)
            B[ni] = *(const f16x8*)&Wf[(((blockIdx.y * 4 + ni) * kcN + kc) * 64 + lane) * 8];
#pragma unroll
        for (int mi = 0; mi < 2; ++mi)
#pragma unroll
            for (int ni = 0; ni < 4; ++ni)
                acc[mi][ni] = __builtin_amdgcn_mfma_f32_16x16x32_f16(
                    A[mi], B[ni], acc[mi][ni], 0, 0, 0);
    }

    float bv[4];
#pragma unroll
    for (int ni = 0; ni < 4; ++ni) bv[ni] = BIAS ? bias[oc0 + ni * 16 + n16] : 0.f;

    float lsum = 0.f, lsq = 0.f;
#pragma unroll
    for (int mi = 0; mi < 2; ++mi)
#pragma unroll
        for (int r = 0; r < 4; ++r) {
            const int pix = p0 + w * 32 + mi * 16 + quad * 4 + r;
            const size_t ob = ((size_t)z * HW + pix) * (size_t)Mtot + oc0;
            const size_t rb = ((size_t)z * HW + pix) * 128 + oc0;
#pragma unroll
            for (int ni = 0; ni < 4; ++ni) {
                float tv = acc[mi][ni][r] + bv[ni];
                if (LRELU) tv = tv >= 0.f ? tv : 0.2f * tv;
                if (RESID) tv += (float)resid[rb + ni * 16 + n16];
                if (REDUCE) { lsum += tv; lsq += tv * tv; }
                if (OUTF16) ((_Float16*)Yv)[ob + ni * 16 + n16] = (_Float16)tv;
                else        ((float*)Yv)[ob + ni * 16 + n16] = tv;
            }
        }

    if (REDUCE) {
        __shared__ float red[4];
#pragma unroll
        for (int m = 1; m < 64; m <<= 1) {
            lsum += __shfl_xor(lsum, m, 64);
            lsq  += __shfl_xor(lsq,  m, 64);
        }
        if (lane == 0) { red[w * 2] = lsum; red[w * 2 + 1] = lsq; }
        __syncthreads();
        if (tid == 0) {
            const int bid = (blockIdx.z * gridDim.y + blockIdx.y) * gridDim.x + blockIdx.x;
            pb[bid * 2 + 0] = red[0] + red[2];
            pb[bid * 2 + 1] = red[1] + red[3];
        }
    }
}

// ---------------------------------------------------------------------------
// Deformable window attention, 4 pixels per wave (16 lanes/pixel, 8 ch/lane).
// q,k,v f16 NHWC. QK via v_dot2_f32_f16; PV via mixed fma (fp32 acc).
// Separable (Wy x Wx) spread of attn into the 6x6 tap field.
// ---------------------------------------------------------------------------
__global__ void __launch_bounds__(256)
attn_k(const _Float16* __restrict__ q, const _Float16* __restrict__ k,
       const _Float16* __restrict__ v, const float* __restrict__ df,
       _Float16* __restrict__ out)
{
    const int blk = blockIdx.x;
    const int sw = (blk & 7) * (1152 / 8) + (blk >> 3);   // XCD band swizzle
    const int wv = sw * 4 + (threadIdx.x >> 6);
    const int lane = threadIdx.x & 63;
    const int gp = wv * 4 + (lane >> 4);                  // global pixel
    const int b = gp / HW;
    const int pix = gp - b * HW;
    const int y = pix / Ww, x = pix - y * Ww;
    const int co = (lane & 15) * 8;                       // channel offset

    const float dx = df[((size_t)b * 2 + 0) * HW + pix];
    const float dy = df[((size_t)b * 2 + 1) * HW + pix];
    const float flx = floorf(dx), fly = floorf(dy);
    const int bx = x - 2 + (int)flx;
    const int by = y - 2 + (int)fly;
    const float wx1 = dx - flx, wx0 = 1.f - wx1;
    const float wy1 = dy - fly, wy0 = 1.f - wy1;
    const float u00 = wy0 * wx0, u01 = wy0 * wx1, u10 = wy1 * wx0, u11 = wy1 * wx1;
    const float s00 = u00 * 0.25f, s01 = u01 * 0.25f,
                s10 = u10 * 0.25f, s11 = u11 * 0.25f;

    const f16x8 qv8 = *(const f16x8*)&q[((size_t)b * HW + pix) * Cc + co];
    const f16x2 q0 = {qv8[0], qv8[1]}, q1 = {qv8[2], qv8[3]},
                q2 = {qv8[4], qv8[5]}, q3 = {qv8[6], qv8[7]};

    const _Float16* kp = k + ((size_t)b * HW) * Cc + co;
    const _Float16* vp = v + ((size_t)b * HW) * Cc + co;

    const bool inb = (bx >= 0) & (by >= 0) & (bx <= Ww - 6) & (by <= Hh - 6);
    const int allin = __all(inb);

    float qk[36];
    if (allin) {
        const _Float16* kr = kp + (size_t)(by * Ww + bx) * Cc;
#pragma unroll
        for (int r = 0; r < 6; ++r) {
#pragma unroll
            for (int c = 0; c < 6; ++c) {
                const f16x8 kv = *(const f16x8*)&kr[c * Cc];
                f16x2 k0 = {kv[0], kv[1]}, k1 = {kv[2], kv[3]};
                f16x2 k2 = {kv[4], kv[5]}, k3 = {kv[6], kv[7]};
                float d = fdot2(q0, k0, 0.f);
                d = fdot2(q1, k1, d);
                d = fdot2(q2, k2, d);
                d = fdot2(q3, k3, d);
                qk[r * 6 + c] = d;
            }
            kr += Ww * Cc;
        }
    } else {
#pragma unroll
        for (int r = 0; r < 6; ++r) {
            const int yr = by + r;
            const bool rv = (yr >= 0) & (yr < Hh);
            const int yc = min(max(yr, 0), Hh - 1);
            const _Float16* kr = kp + (size_t)(yc * Ww) * Cc;
#pragma unroll
            for (int c = 0; c < 6; ++c) {
                const int xc = bx + c;
                const bool cv = rv & (xc >= 0) & (xc < Ww);
                const int xcc = min(max(xc, 0), Ww - 1);
                const f16x8 kv = *(const f16x8*)&kr[xcc * Cc];
                f16x2 k0 = {kv[0], kv[1]}, k1 = {kv[2], kv[3]};
                f16x2 k2 = {kv[4], kv[5]}, k3 = {kv[6], kv[7]};
                float d = fdot2(q0, k0, 0.f);
                d = fdot2(q1, k1, d);
                d = fdot2(q2, k2, d);
                d = fdot2(q3, k3, d);
                qk[r * 6 + c] = cv ? d : 0.f;
            }
        }
    }

    float a[25];
#pragma unroll
    for (int py = 0; py < 5; ++py)
#pragma unroll
        for (int px = 0; px < 5; ++px) {
            float tv = s00 * qk[py * 6 + px];
            tv = fmaf(s01, qk[py * 6 + px + 1], tv);
            tv = fmaf(s10, qk[(py + 1) * 6 + px], tv);
            tv = fmaf(s11, qk[(py + 1) * 6 + px + 1], tv);
            a[py * 5 + px] = tv;
        }
#pragma unroll
    for (int i = 0; i < 25; ++i) a[i] += __shfl_xor(a[i], 1, 64);

    float mx = a[0];
#pragma unroll
    for (int i = 1; i < 25; ++i) mx = fmaxf(mx, a[i]);
    float ssum = 0.f;
#pragma unroll
    for (int i = 0; i < 25; ++i) { a[i] = __expf(a[i] - mx); ssum += a[i]; }
    const float inv = 1.f / ssum;

    // separable spread: rows (Wy) then cols (Wx)
    float tmp[6][5];
#pragma unroll
    for (int r = 0; r < 6; ++r)
#pragma unroll
        for (int px = 0; px < 5; ++px) {
            float tv = 0.f;
            if (r < 5)  tv = a[r * 5 + px] * wy0;
            if (r >= 1) tv = fmaf(a[(r - 1) * 5 + px], wy1, tv);
            tmp[r][px] = tv;
        }
    float wsum[36];
#pragma unroll
    for (int r = 0; r < 6; ++r)
#pragma unroll
        for (int c = 0; c < 6; ++c) {
            float tv = 0.f;
            if (c < 5)  tv = tmp[r][c] * wx0;
            if (c >= 1) tv = fmaf(tmp[r][c - 1], wx1, tv);
            wsum[r * 6 + c] = tv;
        }

    float o[8] = {0.f, 0.f, 0.f, 0.f, 0.f, 0.f, 0.f, 0.f};
    if (allin) {
        const _Float16* vr = vp + (size_t)(by * Ww + bx) * Cc;
#pragma unroll
        for (int r = 0; r < 6; ++r) {
#pragma unroll
            for (int c = 0; c < 6; ++c) {
                const f16x8 vv = *(const f16x8*)&vr[c * Cc];
                const float wgt = wsum[r * 6 + c];
#pragma unroll
                for (int j = 0; j < 8; ++j)
                    o[j] = fmaf(wgt, (float)vv[j], o[j]);
            }
            vr += Ww * Cc;
        }
    } else {
#pragma unroll
        for (int r = 0; r < 6; ++r) {
            const int yr = by + r;
            const bool rv = (yr >= 0) & (yr < Hh);
            const int yc = min(max(yr, 0), Hh - 1);
            const _Float16* vr = vp + (size_t)(yc * Ww) * Cc;
#pragma unroll
            for (int c = 0; c < 6; ++c) {
                const int xc = bx + c;
                const bool cv = rv & (xc >= 0) & (xc < Ww);
                const int xcc = min(max(xc, 0), Ww - 1);
                const f16x8 vv = *(const f16x8*)&vr[xcc * Cc];
                const float wgt = cv ? wsum[r * 6 + c] : 0.f;
#pragma unroll
                for (int j = 0; j < 8; ++j)
                    o[j] = fmaf(wgt, (float)vv[j], o[j]);
            }
        }
    }

    f16x8 ov;
#pragma unroll
    for (int j = 0; j < 8; ++j) ov[j] = (_Float16)(o[j] * inv);
    *(f16x8*)&out[((size_t)b * HW + pix) * Cc + co] = ov;
}

// ---------------------------------------------------------------------------
// GroupNorm finalize + NHWC fp32 -> NCHW fp32 transpose, with inline
// reduction of the mlp2 per-block partials. grid (HW/64, Cc/32, Nn), block 256.
// ---------------------------------------------------------------------------
__global__ void __launch_bounds__(256)
gn_k(const float* __restrict__ y2, const float* __restrict__ pb,
     const float* __restrict__ gamma, const float* __restrict__ beta,
     float* __restrict__ out, const int nPerZ)
{
    __shared__ float t[32][68];
    __shared__ float redm[8];
    __shared__ float stats[2];
    const int z = blockIdx.z, c0 = blockIdx.y * 32, p0 = blockIdx.x * 64;
    const int tid = threadIdx.x;

    // inline partial reduction (L2-hot, 2.3 KB per z)
    {
        float s = 0.f, qq = 0.f;
        for (int p = tid; p < nPerZ; p += 256) {
            s  += pb[(z * nPerZ + p) * 2 + 0];
            qq += pb[(z * nPerZ + p) * 2 + 1];
        }
#pragma unroll
        for (int m = 1; m < 64; m <<= 1) {
            s  += __shfl_xor(s,  m, 64);
            qq += __shfl_xor(qq, m, 64);
        }
        if ((tid & 63) == 0) {
            redm[(tid >> 6) * 2]     = s;
            redm[(tid >> 6) * 2 + 1] = qq;
        }
    }
    // stage the transpose tile
    {
        const int px = tid >> 2, cq = tid & 3;
        const float* src = &y2[((size_t)z * HW + p0 + px) * Cc + c0 + cq * 8];
        const float4 a = *(const float4*)src;
        const float4 bq = *(const float4*)(src + 4);
        t[cq * 8 + 0][px] = a.x;  t[cq * 8 + 1][px] = a.y;
        t[cq * 8 + 2][px] = a.z;  t[cq * 8 + 3][px] = a.w;
        t[cq * 8 + 4][px] = bq.x; t[cq * 8 + 5][px] = bq.y;
        t[cq * 8 + 6][px] = bq.z; t[cq * 8 + 7][px] = bq.w;
    }
    __syncthreads();
    if (tid == 0) {
        const float invN = 1.f / (float)(Cc * HW);
        const float S = redm[0] + redm[2] + redm[4] + redm[6];
        const float Q = redm[1] + redm[3] + redm[5] + redm[7];
        const float mean = S * invN;
        const float var  = fmaf(-mean, mean, Q * invN);
        stats[0] = mean;
        stats[1] = rsqrtf(var + 1e-5f);
    }
    __syncthreads();
    {
        const float mean = stats[0], rs = stats[1];
        const int c = tid >> 3, pq = tid & 7;
        const float g = gamma[c0 + c] * rs, be = beta[c0 + c];
        float4 o1, o2;
        o1.x = fmaf(t[c][pq * 8 + 0] - mean, g, be);
        o1.y = fmaf(t[c][pq * 8 + 1] - mean, g, be);
        o1.z = fmaf(t[c][pq * 8 + 2] - mean, g, be);
        o1.w = fmaf(t[c][pq * 8 + 3] - mean, g, be);
        o2.x = fmaf(t[c][pq * 8 + 4] - mean, g, be);
        o2.y = fmaf(t[c][pq * 8 + 5] - mean, g, be);
        o2.z = fmaf(t[c][pq * 8 + 6] - mean, g, be);
        o2.w = fmaf(t[c][pq * 8 + 7] - mean, g, be);
        float* dst = &out[((size_t)z * Cc + c0 + c) * HW + p0 + pq * 8];
        *(float4*)dst = o1;
        *(float4*)(dst + 4) = o2;
    }
}

// ---------------------------------------------------------------------------
extern "C" void kernel_launch(void* const* d_in, const int* in_sizes, int n_in,
                              void* d_out, int out_size, void* d_ws, size_t ws_size,
                              hipStream_t stream)
{
    const float* query  = (const float*)d_in[0];
    const float* key    = (const float*)d_in[1];
    const float* value  = (const float*)d_in[2];
    const float* deform = (const float*)d_in[3];
    const float* w_q    = (const float*)d_in[4];
    const float* w_k    = (const float*)d_in[5];
    const float* w_v    = (const float*)d_in[6];
    const float* w_fc   = (const float*)d_in[7];
    const float* mlp_w1 = (const float*)d_in[8];
    const float* mlp_b1 = (const float*)d_in[9];
    const float* mlp_w2 = (const float*)d_in[10];
    const float* mlp_b2 = (const float*)d_in[11];
    const float* gn_g   = (const float*)d_in[12];
    const float* gn_b   = (const float*)d_in[13];
    float* out = (float*)d_out;

    // workspace layout
    char* wsb = (char*)d_ws;
    _Float16* w16 = (_Float16*)wsb;                  // 131072 halves, frag order
    float* pb   = (float*)(wsb + 262144);            // per-block partials
    _Float16* T = (_Float16*)(wsb + 524288);
    const size_t S16 = (size_t)Nn * HW * Cc;         // halves per f16 tensor
    _Float16* q16  = T;                              // R0
    _Float16* k16  = T + S16;                        // R1
    _Float16* v16  = T + 2 * S16;                    // R2
    _Float16* at16 = T + 3 * S16;                    // R3
    _Float16* y1   = T + 4 * S16;                    // R4
    _Float16* hb   = T;                              // R0+R1 (q,k dead after attn)
    float*    y2   = (float*)(T + 2 * S16);          // R2+R3 (v,at dead by mlp2)

    // weights -> f16 fragment order
    wcvt_k<<<dim3(64), dim3(256), 0, stream>>>(
        w_q, w_k, w_v, w_fc, mlp_w1, mlp_w2, w16);

    // fused q/k/v projections -> f16 NHWC
    qkv_k<<<dim3(HW / 64, 3, Nn), dim3(128), 0, stream>>>(
        query, key, value, w16, q16, k16, v16);

    // deformable window attention -> f16 NHWC
    attn_k<<<dim3(Nn * HW / 16), dim3(256), 0, stream>>>(
        q16, k16, v16, deform, at16);

    // fc: y1 = wfc @ attn
    mg_k<128, true, false, false, false, false>
        <<<dim3(HW / 64, 2, Nn), dim3(128), 0, stream>>>(
        at16, w16 + 49152, nullptr, nullptr, y1, nullptr, 128);

    // mlp hidden: h = lrelu(w1 @ y1 + b1)
    mg_k<128, true, true, true, false, false>
        <<<dim3(HW / 64, 4, Nn), dim3(128), 0, stream>>>(
        y1, w16 + 65536, mlp_b1, nullptr, hb, nullptr, 256);

    // y2 = y1 + w2 @ h + b2 (fp32 NHWC), per-block partial sums
    mg_k<256, false, true, false, true, true>
        <<<dim3(HW / 64, 2, Nn), dim3(128), 0, stream>>>(
        hb, w16 + 98304, mlp_b2, y1, y2, pb, 128);

    // GroupNorm finalize (inline partial reduce) + NHWC->NCHW
    gn_k<<<dim3(HW / 64, Cc / 32, Nn), dim3(256), 0, stream>>>(
        y2, pb, gn_g, gn_b, out, 288);
}